// Round 1
// baseline (1065.929 us; speedup 1.0000x reference)
//
#include <hip/hip_runtime.h>

// Max pool 2x2 stride 2, NCHW fp32.
// In:  (32, 128, 224, 224)  Out: (32, 128, 112, 112)
// One thread computes 4 output columns via float4 loads/stores.

#define IN_W   224
#define IN_HW  (224 * 224)
#define OUT_W  112
#define OUT_HW (112 * 112)
#define GROUPS_PER_ROW (OUT_W / 4)   // 28

__global__ __launch_bounds__(256) void pool2d_kernel(
    const float* __restrict__ in, float* __restrict__ out, int n_groups) {
    int g = blockIdx.x * blockDim.x + threadIdx.x;
    if (g >= n_groups) return;

    // g -> (row over N*C*H_out, column group of 4 outputs)
    int cg  = g % GROUPS_PER_ROW;          // compiler emits magic-mul for /28
    int row = g / GROUPS_PER_ROW;          // row in [0, N*C*112)
    int h_out = row % OUT_W;               // 112 output rows per image plane
    int nc    = row / OUT_W;

    const float* base0 = in + (size_t)nc * IN_HW + (size_t)(2 * h_out) * IN_W + cg * 8;
    const float* base1 = base0 + IN_W;

    float4 a = *(const float4*)(base0);      // row0 cols c..c+3
    float4 b = *(const float4*)(base0 + 4);  // row0 cols c+4..c+7
    float4 c = *(const float4*)(base1);      // row1 cols c..c+3
    float4 d = *(const float4*)(base1 + 4);  // row1 cols c+4..c+7

    float4 o;
    o.x = fmaxf(fmaxf(a.x, a.y), fmaxf(c.x, c.y));
    o.y = fmaxf(fmaxf(a.z, a.w), fmaxf(c.z, c.w));
    o.z = fmaxf(fmaxf(b.x, b.y), fmaxf(d.x, d.y));
    o.w = fmaxf(fmaxf(b.z, b.w), fmaxf(d.z, d.w));

    *(float4*)(out + (size_t)row * OUT_W + cg * 4) = o;
}

extern "C" void kernel_launch(void* const* d_in, const int* in_sizes, int n_in,
                              void* d_out, int out_size, void* d_ws, size_t ws_size,
                              hipStream_t stream) {
    const float* x = (const float*)d_in[0];
    float* y = (float*)d_out;

    // total output elements = 32*128*112*112 = 51,380,224; groups of 4:
    int n_groups = out_size / 4;  // 12,845,056
    int block = 256;
    int grid = (n_groups + block - 1) / block;  // 50,176
    pool2d_kernel<<<grid, block, 0, stream>>>(x, y, n_groups);
}